// Round 1
// baseline (1225.615 us; speedup 1.0000x reference)
//
#include <hip/hip_runtime.h>
#include <hip/hip_fp16.h>
#include <stdint.h>

#define LT 512   // timesteps
#define NB 512   // batch
#define DI 128   // input dim
#define DH 128   // hidden dim
#define G4 512   // 4*H gates

typedef _Float16 f16;
typedef __attribute__((ext_vector_type(2))) _Float16 f16x2;

__device__ __forceinline__ float dot2f(uint32_t a, uint32_t b, float c) {
#if __has_builtin(__builtin_amdgcn_fdot2)
    return __builtin_amdgcn_fdot2(__builtin_bit_cast(f16x2, a),
                                  __builtin_bit_cast(f16x2, b), c, false);
#else
    f16x2 pa = __builtin_bit_cast(f16x2, a);
    f16x2 pb = __builtin_bit_cast(f16x2, b);
    return c + (float)pa.x * (float)pb.x + (float)pa.y * (float)pb.y;
#endif
}

__device__ __forceinline__ uint32_t pack2(float x, float y) {
    f16x2 p;
    p.x = (_Float16)x;
    p.y = (_Float16)y;
    return __builtin_bit_cast(uint32_t, p);
}

__device__ __forceinline__ float sigm(float v) {
    return 1.f / (1.f + __expf(-v));
}

__device__ __forceinline__ float tanh_(float v) {
    float a = fabsf(v);
    float e = __expf(-2.f * a);          // in (0,1], never overflows
    float r = (1.f - e) / (1.f + e);
    return v < 0.f ? -r : r;
}

// One block owns 2 batch rows for all 512 timesteps.
// thread g in [0,512) computes gate g for both rows each step.
// W_ih/W_hh rows live packed-f16 in registers (64+64 u32) for the whole kernel.
__launch_bounds__(512, 2)
__global__ void lstm_fused(const float* __restrict__ x,      // [L][N][I]
                           const float* __restrict__ hc0,    // [N][2H]
                           const int*   __restrict__ isini,  // [L][N]
                           const float* __restrict__ Wih,    // [4H][I]
                           const float* __restrict__ Whh,    // [4H][H]
                           const float* __restrict__ bih,    // [4H]
                           const float* __restrict__ bhh,    // [4H]
                           float* __restrict__ out)          // [L][N][H] ++ [N][2H]
{
    const int g   = threadIdx.x;      // gate id 0..511
    const int n0  = blockIdx.x * 2;   // first of my 2 batch rows

    __shared__ __align__(16) f16   sh_h[2][DH];        // packed h per row
    __shared__ __align__(16) f16   sh_x[2][2][DI];     // double-buffered x per row
    __shared__ __align__(16) float sh_gates[2][G4];    // raw gate pre-activations

    // ---- load my weight rows, packed f16 (held in VGPRs for entire kernel) ----
    uint32_t wih[64], whh[64];
    {
        const float4* wi = (const float4*)(Wih + (size_t)g * DI);
        const float4* wh = (const float4*)(Whh + (size_t)g * DI);
#pragma unroll
        for (int i = 0; i < 32; ++i) {
            float4 a = wi[i];
            wih[2 * i]     = pack2(a.x, a.y);
            wih[2 * i + 1] = pack2(a.z, a.w);
            float4 b = wh[i];
            whh[2 * i]     = pack2(b.x, b.y);
            whh[2 * i + 1] = pack2(b.z, b.w);
        }
    }
    const float bias = bih[g] + bhh[g];

    // roles: tid<256 = cell/state threads (row=tid>>7, j=tid&127)
    //        tid>=256 = x-prefetch threads (same row/j mapping)
    const int row = (threadIdx.x >> 7) & 1;
    const int j   = threadIdx.x & 127;
    const int n   = n0 + row;

    float cval = 0.f, hval = 0.f;

    if (threadIdx.x < 256) {
        // initial c in register, initial h -> LDS (f16)
        cval = hc0[(size_t)n * (2 * DH) + DH + j];
        float h0 = hc0[(size_t)n * (2 * DH) + j];
        sh_h[row][j] = (f16)h0;
    } else {
        // stage x[t=0]
        float xv0 = x[((size_t)0 * NB + n) * DI + j];
        sh_x[0][row][j] = (f16)xv0;
    }
    __syncthreads();

    for (int t = 0; t < LT; ++t) {
        // episode-reset mask for this step (uniform per block -> scalarized)
        const float m0 = 1.f - (float)isini[(size_t)t * NB + n0];
        const float m1 = 1.f - (float)isini[(size_t)t * NB + n0 + 1];

        // issue prefetch of x[t+1] early (latency hidden under dot loop)
        float xpre = 0.f;
        if (threadIdx.x >= 256) {
            int tp = (t + 1 < LT) ? (t + 1) : (LT - 1);
            xpre = x[((size_t)tp * NB + n) * DI + j];
        }

        // ---- gate dot products: gate = bias + x.Wih + m * (h.Whh) ----
        const uint4* xp0 = (const uint4*)&sh_x[t & 1][0][0];
        const uint4* xp1 = (const uint4*)&sh_x[t & 1][1][0];
        const uint4* hp0 = (const uint4*)&sh_h[0][0];
        const uint4* hp1 = (const uint4*)&sh_h[1][0];

        float ax0 = 0.f, ax0b = 0.f, ah0 = 0.f, ah0b = 0.f;
        float ax1 = 0.f, ax1b = 0.f, ah1 = 0.f, ah1b = 0.f;
#pragma unroll
        for (int i = 0; i < 16; ++i) {
            uint4 xv0 = xp0[i];
            uint4 xv1 = xp1[i];
            uint4 hv0 = hp0[i];
            uint4 hv1 = hp1[i];
            ax0  = dot2f(xv0.x, wih[4 * i + 0], ax0);
            ax0b = dot2f(xv0.y, wih[4 * i + 1], ax0b);
            ax0  = dot2f(xv0.z, wih[4 * i + 2], ax0);
            ax0b = dot2f(xv0.w, wih[4 * i + 3], ax0b);
            ah0  = dot2f(hv0.x, whh[4 * i + 0], ah0);
            ah0b = dot2f(hv0.y, whh[4 * i + 1], ah0b);
            ah0  = dot2f(hv0.z, whh[4 * i + 2], ah0);
            ah0b = dot2f(hv0.w, whh[4 * i + 3], ah0b);
            ax1  = dot2f(xv1.x, wih[4 * i + 0], ax1);
            ax1b = dot2f(xv1.y, wih[4 * i + 1], ax1b);
            ax1  = dot2f(xv1.z, wih[4 * i + 2], ax1);
            ax1b = dot2f(xv1.w, wih[4 * i + 3], ax1b);
            ah1  = dot2f(hv1.x, whh[4 * i + 0], ah1);
            ah1b = dot2f(hv1.y, whh[4 * i + 1], ah1b);
            ah1  = dot2f(hv1.z, whh[4 * i + 2], ah1);
            ah1b = dot2f(hv1.w, whh[4 * i + 3], ah1b);
        }
        sh_gates[0][g] = bias + (ax0 + ax0b) + m0 * (ah0 + ah0b);
        sh_gates[1][g] = bias + (ax1 + ax1b) + m1 * (ah1 + ah1b);

        __syncthreads();   // gates visible

        if (threadIdx.x < 256) {
            // PyTorch LSTMCell gate order: i, f, g, o
            float ig = sh_gates[row][j];
            float fg = sh_gates[row][128 + j];
            float gg = sh_gates[row][256 + j];
            float og = sh_gates[row][384 + j];
            float m  = row ? m1 : m0;
            float cc = m * cval;
            cc   = sigm(fg) * cc + sigm(ig) * tanh_(gg);
            hval = sigm(og) * tanh_(cc);
            cval = cc;
            out[((size_t)t * NB + n) * DH + j] = hval;
            sh_h[row][j] = (f16)hval;
        } else {
            sh_x[(t + 1) & 1][row][j] = (f16)xpre;
        }

        __syncthreads();   // h / next-x visible
    }

    // final state: hc_out[n] = [h_n, c_n]  (N==L makes broadcast an identity)
    if (threadIdx.x < 256) {
        size_t base = (size_t)LT * NB * DH;
        out[base + (size_t)n * (2 * DH) + j]      = hval;
        out[base + (size_t)n * (2 * DH) + DH + j] = cval;
    }
}

extern "C" void kernel_launch(void* const* d_in, const int* in_sizes, int n_in,
                              void* d_out, int out_size, void* d_ws, size_t ws_size,
                              hipStream_t stream) {
    const float* x     = (const float*)d_in[0];
    const float* hc0   = (const float*)d_in[1];
    const int*   isini = (const int*)d_in[2];
    const float* Wih   = (const float*)d_in[3];
    const float* Whh   = (const float*)d_in[4];
    const float* bih   = (const float*)d_in[5];
    const float* bhh   = (const float*)d_in[6];
    float* out = (float*)d_out;

    lstm_fused<<<dim3(NB / 2), dim3(512), 0, stream>>>(
        x, hc0, isini, Wih, Whh, bih, bhh, out);
}

// Round 2
// 882.775 us; speedup vs baseline: 1.3884x; 1.3884x over previous
//
#include <hip/hip_runtime.h>
#include <hip/hip_fp16.h>
#include <stdint.h>

#define LT 512   // timesteps
#define NB 512   // batch
#define DI 128   // input dim
#define DH 128   // hidden dim
#define G4 512   // 4*H gates
#define MROWS (LT * NB)   // 262144 flat (t,n) rows

typedef _Float16 f16;
typedef __attribute__((ext_vector_type(2))) _Float16 f16x2;
typedef __attribute__((ext_vector_type(8))) _Float16 f16x8;
typedef __attribute__((ext_vector_type(4))) float floatx4;

__device__ __forceinline__ float dot2f(uint32_t a, uint32_t b, float c) {
#if __has_builtin(__builtin_amdgcn_fdot2)
    return __builtin_amdgcn_fdot2(__builtin_bit_cast(f16x2, a),
                                  __builtin_bit_cast(f16x2, b), c, false);
#else
    f16x2 pa = __builtin_bit_cast(f16x2, a);
    f16x2 pb = __builtin_bit_cast(f16x2, b);
    return c + (float)pa.x * (float)pb.x + (float)pa.y * (float)pb.y;
#endif
}

__device__ __forceinline__ uint32_t pack2(float x, float y) {
    f16x2 p;
    p.x = (_Float16)x;
    p.y = (_Float16)y;
    return __builtin_bit_cast(uint32_t, p);
}

__device__ __forceinline__ float sigm(float v) {
    return 1.f / (1.f + __expf(-v));
}

__device__ __forceinline__ float tanh_(float v) {
    float a = fabsf(v);
    float e = __expf(-2.f * a);
    float r = (1.f - e) / (1.f + e);
    return v < 0.f ? -r : r;
}

// ============================================================================
// Kernel 1: gx[m][g] = sum_k x[m][k] * Wih[g][k]   (f16 out, no bias)
// MFMA 16x16x32_f16. Block = 512 thr = 8 waves, tile = 128 rows x 256 gates.
// grid.x = (MROWS/128) * 2 gate-halves = 4096.
// A (x-tile) staged f16 in LDS, frag-ordered + XOR-swizzled (2-way banks, free).
// B (weights) loaded per-wave straight from global (L2-hot, tiny).
// ============================================================================
__launch_bounds__(512, 4)
__global__ void gemm_xgates(const float* __restrict__ x,
                            const float* __restrict__ Wih,
                            f16* __restrict__ gx)
{
    __shared__ uint4 wx[128 * 16];   // 32 KB: 128 rows x 16 uint4 (8 f16 each)
    const int tid = threadIdx.x;
    const int bm  = blockIdx.x >> 1;   // row-tile
    const int gh  = blockIdx.x & 1;    // gate half (0: gates 0..255, 1: 256..511)
    const size_t rowbase = (size_t)bm * 128;

    // ---- stage x-tile -> LDS as f16 frags (each thread: 128B contiguous) ----
    {
        const float4* src = (const float4*)(x + rowbase * DI) + (size_t)tid * 8;
#pragma unroll
        for (int i = 0; i < 4; ++i) {
            float4 a = src[2 * i];
            float4 b = src[2 * i + 1];
            uint4 u;
            u.x = pack2(a.x, a.y); u.y = pack2(a.z, a.w);
            u.z = pack2(b.x, b.y); u.w = pack2(b.z, b.w);
            int flat = tid * 4 + i;        // uint4 index in row-major frag order
            int row  = flat >> 4;          // 0..127
            int m    = flat & 15;          // = kc*4+quad
            wx[row * 16 + (m ^ (row & 15))] = u;
        }
    }

    const int lane = tid & 63;
    const int w    = tid >> 6;       // wave 0..7
    const int l16  = lane & 15;
    const int quad = lane >> 4;

    // ---- B-frags: wave handles 2 gate-tiles (32 gates), held in 32 VGPRs ----
    f16x8 bfrag[2][4];
#pragma unroll
    for (int p = 0; p < 2; ++p) {
        int gate = (gh * 16 + w * 2 + p) * 16 + l16;
        const float4* wp = (const float4*)(Wih + (size_t)gate * DI);
#pragma unroll
        for (int kc = 0; kc < 4; ++kc) {
            float4 a = wp[kc * 8 + quad * 2];
            float4 b = wp[kc * 8 + quad * 2 + 1];
            uint4 u;
            u.x = pack2(a.x, a.y); u.y = pack2(a.z, a.w);
            u.z = pack2(b.x, b.y); u.w = pack2(b.z, b.w);
            bfrag[p][kc] = __builtin_bit_cast(f16x8, u);
        }
    }
    __syncthreads();

    // ---- 8 row-sets of 16: A from LDS, 8 MFMAs, store f16 ----
#pragma unroll
    for (int rs = 0; rs < 8; ++rs) {
        f16x8 afrag[4];
        int row = rs * 16 + l16;
#pragma unroll
        for (int kc = 0; kc < 4; ++kc) {
            int m = kc * 4 + quad;
            afrag[kc] = __builtin_bit_cast(f16x8, wx[row * 16 + (m ^ (row & 15))]);
        }
        floatx4 acc0 = {0.f, 0.f, 0.f, 0.f};
        floatx4 acc1 = {0.f, 0.f, 0.f, 0.f};
#pragma unroll
        for (int kc = 0; kc < 4; ++kc) {
            acc0 = __builtin_amdgcn_mfma_f32_16x16x32_f16(afrag[kc], bfrag[0][kc], acc0, 0, 0, 0);
            acc1 = __builtin_amdgcn_mfma_f32_16x16x32_f16(afrag[kc], bfrag[1][kc], acc1, 0, 0, 0);
        }
        // C/D layout: col = lane&15, row = quad*4 + reg  [verified, guide §3]
        size_t orow = rowbase + (size_t)rs * 16 + quad * 4;
        int col0 = (gh * 16 + w * 2 + 0) * 16 + l16;
        int col1 = col0 + 16;
#pragma unroll
        for (int r = 0; r < 4; ++r) {
            gx[(orow + r) * G4 + col0] = (f16)acc0[r];
            gx[(orow + r) * G4 + col1] = (f16)acc1[r];
        }
    }
}

// ============================================================================
// Kernel 2: recurrence only. 1 batch row per block, 512 blocks (2 per CU),
// thread = gate g; Whh row in 64 VGPRs; h broadcast from LDS (16 b128/step).
// x-gates come precomputed (f16) from kernel 1.
// ============================================================================
__launch_bounds__(512, 4)
__global__ void lstm_rec(const f16* __restrict__ gx,     // [L*N][512]
                         const float* __restrict__ hc0,  // [N][2H]
                         const int*   __restrict__ isini, // [L][N]
                         const float* __restrict__ Whh,  // [4H][H]
                         const float* __restrict__ bih,  // [4H]
                         const float* __restrict__ bhh,  // [4H]
                         float* __restrict__ out)        // [L][N][H] ++ [N][2H]
{
    const int g = threadIdx.x;   // gate 0..511
    const int n = blockIdx.x;    // batch row

    __shared__ __align__(16) f16 sh_h[DH];
    __shared__ float sh_gates[G4];

    // Whh row g, packed f16 -> 64 VGPRs, resident for whole kernel
    uint32_t whh[64];
    {
        const float4* wh = (const float4*)(Whh + (size_t)g * DH);
#pragma unroll
        for (int i = 0; i < 32; ++i) {
            float4 b = wh[i];
            whh[2 * i]     = pack2(b.x, b.y);
            whh[2 * i + 1] = pack2(b.z, b.w);
        }
    }
    const float bg = bih[g] + bhh[g];
    const int j = g & 127;

    float cval = 0.f, hval = 0.f;
    if (g < 128) {
        cval = hc0[(size_t)n * (2 * DH) + DH + j];
        sh_h[j] = (f16)hc0[(size_t)n * (2 * DH) + j];
    }

    // prefetched state for step t
    f16   gxv = gx[(size_t)n * G4 + g];          // t = 0
    float mv  = 1.f - (float)isini[n];           // t = 0
    __syncthreads();

    for (int t = 0; t < LT; ++t) {
        // issue next-step prefetch first (hides global latency under dots)
        int tn = (t + 1 < LT) ? (t + 1) : (LT - 1);
        f16   gxn = gx[((size_t)tn * NB + n) * G4 + g];
        float mn  = 1.f - (float)isini[(size_t)tn * NB + n];

        // ---- h . Whh[g] : 16 broadcast b128 reads + 64 dot2 ----
        const uint4* hp = (const uint4*)sh_h;
        float a0 = 0.f, a1 = 0.f, a2 = 0.f, a3 = 0.f;
#pragma unroll
        for (int i = 0; i < 8; ++i) {
            uint4 h0 = hp[2 * i];
            uint4 h1 = hp[2 * i + 1];
            a0 = dot2f(h0.x, whh[8 * i + 0], a0);
            a1 = dot2f(h0.y, whh[8 * i + 1], a1);
            a2 = dot2f(h0.z, whh[8 * i + 2], a2);
            a3 = dot2f(h0.w, whh[8 * i + 3], a3);
            a0 = dot2f(h1.x, whh[8 * i + 4], a0);
            a1 = dot2f(h1.y, whh[8 * i + 5], a1);
            a2 = dot2f(h1.z, whh[8 * i + 6], a2);
            a3 = dot2f(h1.w, whh[8 * i + 7], a3);
        }
        sh_gates[g] = (float)gxv + bg + mv * ((a0 + a1) + (a2 + a3));

        float msave = mv;
        __syncthreads();   // gates visible

        if (g < 128) {
            // PyTorch LSTMCell gate order: i, f, g, o
            float ig = sh_gates[j];
            float fg = sh_gates[128 + j];
            float gg = sh_gates[256 + j];
            float og = sh_gates[384 + j];
            float cc = msave * cval;
            cc   = sigm(fg) * cc + sigm(ig) * tanh_(gg);
            hval = sigm(og) * tanh_(cc);
            cval = cc;
            out[((size_t)t * NB + n) * DH + j] = hval;
            sh_h[j] = (f16)hval;
        }
        gxv = gxn;
        mv  = mn;
        __syncthreads();   // new h visible
    }

    if (g < 128) {
        size_t base = (size_t)LT * NB * DH;
        out[base + (size_t)n * (2 * DH) + j]      = hval;
        out[base + (size_t)n * (2 * DH) + DH + j] = cval;
    }
}

// ============================================================================
// Fallback (round-1 kernel, verified): used only if ws_size < 268 MB.
// ============================================================================
__launch_bounds__(512, 2)
__global__ void lstm_fused(const float* __restrict__ x,
                           const float* __restrict__ hc0,
                           const int*   __restrict__ isini,
                           const float* __restrict__ Wih,
                           const float* __restrict__ Whh,
                           const float* __restrict__ bih,
                           const float* __restrict__ bhh,
                           float* __restrict__ out)
{
    const int g   = threadIdx.x;
    const int n0  = blockIdx.x * 2;

    __shared__ __align__(16) f16   sh_h[2][DH];
    __shared__ __align__(16) f16   sh_x[2][2][DI];
    __shared__ __align__(16) float sh_gates[2][G4];

    uint32_t wih[64], whh[64];
    {
        const float4* wi = (const float4*)(Wih + (size_t)g * DI);
        const float4* wh = (const float4*)(Whh + (size_t)g * DI);
#pragma unroll
        for (int i = 0; i < 32; ++i) {
            float4 a = wi[i];
            wih[2 * i]     = pack2(a.x, a.y);
            wih[2 * i + 1] = pack2(a.z, a.w);
            float4 b = wh[i];
            whh[2 * i]     = pack2(b.x, b.y);
            whh[2 * i + 1] = pack2(b.z, b.w);
        }
    }
    const float bias = bih[g] + bhh[g];
    const int row = (threadIdx.x >> 7) & 1;
    const int j   = threadIdx.x & 127;
    const int n   = n0 + row;

    float cval = 0.f, hval = 0.f;

    if (threadIdx.x < 256) {
        cval = hc0[(size_t)n * (2 * DH) + DH + j];
        float h0 = hc0[(size_t)n * (2 * DH) + j];
        sh_h[row][j] = (f16)h0;
    } else {
        float xv0 = x[((size_t)0 * NB + n) * DI + j];
        sh_x[0][row][j] = (f16)xv0;
    }
    __syncthreads();

    for (int t = 0; t < LT; ++t) {
        const float m0 = 1.f - (float)isini[(size_t)t * NB + n0];
        const float m1 = 1.f - (float)isini[(size_t)t * NB + n0 + 1];

        float xpre = 0.f;
        if (threadIdx.x >= 256) {
            int tp = (t + 1 < LT) ? (t + 1) : (LT - 1);
            xpre = x[((size_t)tp * NB + n) * DI + j];
        }

        const uint4* xp0 = (const uint4*)&sh_x[t & 1][0][0];
        const uint4* xp1 = (const uint4*)&sh_x[t & 1][1][0];
        const uint4* hp0 = (const uint4*)&sh_h[0][0];
        const uint4* hp1 = (const uint4*)&sh_h[1][0];

        float ax0 = 0.f, ax0b = 0.f, ah0 = 0.f, ah0b = 0.f;
        float ax1 = 0.f, ax1b = 0.f, ah1 = 0.f, ah1b = 0.f;
#pragma unroll
        for (int i = 0; i < 16; ++i) {
            uint4 xv0 = xp0[i];
            uint4 xv1 = xp1[i];
            uint4 hv0 = hp0[i];
            uint4 hv1 = hp1[i];
            ax0  = dot2f(xv0.x, wih[4 * i + 0], ax0);
            ax0b = dot2f(xv0.y, wih[4 * i + 1], ax0b);
            ax0  = dot2f(xv0.z, wih[4 * i + 2], ax0);
            ax0b = dot2f(xv0.w, wih[4 * i + 3], ax0b);
            ah0  = dot2f(hv0.x, whh[4 * i + 0], ah0);
            ah0b = dot2f(hv0.y, whh[4 * i + 1], ah0b);
            ah0  = dot2f(hv0.z, whh[4 * i + 2], ah0);
            ah0b = dot2f(hv0.w, whh[4 * i + 3], ah0b);
            ax1  = dot2f(xv1.x, wih[4 * i + 0], ax1);
            ax1b = dot2f(xv1.y, wih[4 * i + 1], ax1b);
            ax1  = dot2f(xv1.z, wih[4 * i + 2], ax1);
            ax1b = dot2f(xv1.w, wih[4 * i + 3], ax1b);
            ah1  = dot2f(hv1.x, whh[4 * i + 0], ah1);
            ah1b = dot2f(hv1.y, whh[4 * i + 1], ah1b);
            ah1  = dot2f(hv1.z, whh[4 * i + 2], ah1);
            ah1b = dot2f(hv1.w, whh[4 * i + 3], ah1b);
        }
        sh_gates[0][g] = bias + (ax0 + ax0b) + m0 * (ah0 + ah0b);
        sh_gates[1][g] = bias + (ax1 + ax1b) + m1 * (ah1 + ah1b);

        __syncthreads();

        if (threadIdx.x < 256) {
            float ig = sh_gates[row][j];
            float fg = sh_gates[row][128 + j];
            float gg = sh_gates[row][256 + j];
            float og = sh_gates[row][384 + j];
            float m  = row ? m1 : m0;
            float cc = m * cval;
            cc   = sigm(fg) * cc + sigm(ig) * tanh_(gg);
            hval = sigm(og) * tanh_(cc);
            cval = cc;
            out[((size_t)t * NB + n) * DH + j] = hval;
            sh_h[row][j] = (f16)hval;
        } else {
            sh_x[(t + 1) & 1][row][j] = (f16)xpre;
        }
        __syncthreads();
    }

    if (threadIdx.x < 256) {
        size_t base = (size_t)LT * NB * DH;
        out[base + (size_t)n * (2 * DH) + j]      = hval;
        out[base + (size_t)n * (2 * DH) + DH + j] = cval;
    }
}

extern "C" void kernel_launch(void* const* d_in, const int* in_sizes, int n_in,
                              void* d_out, int out_size, void* d_ws, size_t ws_size,
                              hipStream_t stream) {
    const float* x     = (const float*)d_in[0];
    const float* hc0   = (const float*)d_in[1];
    const int*   isini = (const int*)d_in[2];
    const float* Wih   = (const float*)d_in[3];
    const float* Whh   = (const float*)d_in[4];
    const float* bih   = (const float*)d_in[5];
    const float* bhh   = (const float*)d_in[6];
    float* out = (float*)d_out;

    const size_t need = (size_t)MROWS * G4 * sizeof(f16);   // 268 MB
    if (ws_size >= need) {
        f16* gx = (f16*)d_ws;
        gemm_xgates<<<dim3((MROWS / 128) * 2), dim3(512), 0, stream>>>(x, Wih, gx);
        lstm_rec<<<dim3(NB), dim3(512), 0, stream>>>(gx, hc0, isini, Whh, bih, bhh, out);
    } else {
        lstm_fused<<<dim3(NB / 2), dim3(512), 0, stream>>>(
            x, hc0, isini, Wih, Whh, bih, bhh, out);
    }
}